// Round 17
// baseline (124.844 us; speedup 1.0000x reference)
//
#include <hip/hip_runtime.h>
#include <math.h>

#define S_LEN 2048
#define HID   1024
#define NH    16
#define HD    64
#define NM    128
#define CAUG  192
#define KSPL  2             // K-splits across blocks (grid.z)

constexpr float ALPHA = 0.9f;

typedef __attribute__((ext_vector_type(8))) short bf16x8;
typedef __attribute__((ext_vector_type(4))) short bf16x4;
typedef __attribute__((ext_vector_type(4))) float f32x4;
typedef __attribute__((ext_vector_type(4))) int   int4v;

#define MFMA(a,b,c) __builtin_amdgcn_mfma_f32_16x16x32_bf16(a,b,c,0,0,0)

static __device__ inline short f2bf(float f) {
    unsigned u = __float_as_uint(f);
    u += 0x7fffu + ((u >> 16) & 1u);      // RNE
    return (short)(u >> 16);
}
static __device__ inline float bf2f(short s) {
    return __uint_as_float(((unsigned)(unsigned short)s) << 16);
}

// ---------------------------------------------------------------------------
// fp32 -> bf16 conversion: hs + 4 weights, float4-wide; tail range does the
// omega [h][d][m] -> om_t bf16 [h][m][d] transpose.
// ---------------------------------------------------------------------------
__global__ __launch_bounds__(256)
void conv_kernel(const float* __restrict__ hs,
                 const float* __restrict__ Wq, const float* __restrict__ Wk,
                 const float* __restrict__ Wv, const float* __restrict__ Wo,
                 const float* __restrict__ omega,
                 short* __restrict__ hsb, short* __restrict__ wqb, short* __restrict__ wkb,
                 short* __restrict__ wvb, short* __restrict__ wob, short* __restrict__ omtb)
{
    int i = blockIdx.x * 256 + threadIdx.x;           // f4-unit index
    if (i >= 1605632) return;
    if (i >= 1572864) {                               // omega transpose tail
        int j = (i - 1572864) * 4;                    // elem index in [h][d][m]
        int h = j >> 13, rem = j & 8191;
        int d = rem >> 7, m = rem & 127;
        float4 v = *(const float4*)(omega + j);       // 4 consecutive m
        short* dst = omtb + ((h * 128 + m) << 6) + d; // [h][m][d]
        dst[0]       = f2bf(v.x);
        dst[64]      = f2bf(v.y);
        dst[128]     = f2bf(v.z);
        dst[192]     = f2bf(v.w);
        return;
    }
    const float* src; short* dst; int off;
    if (i < 524288) { src = hs; dst = hsb; off = i; }
    else {
        int j = i - 524288;
        int r = j >> 18;              // 0..3
        off = j & 262143;
        src = (r == 0) ? Wq : (r == 1) ? Wk : (r == 2) ? Wv : Wo;
        dst = (r == 0) ? wqb : (r == 1) ? wkb : (r == 2) ? wvb : wob;
    }
    float4 v = ((const float4*)src)[off];
    bf16x4 o; o[0] = f2bf(v.x); o[1] = f2bf(v.y); o[2] = f2bf(v.z); o[3] = f2bf(v.w);
    ((bf16x4*)dst)[off] = o;
}

// ---------------------------------------------------------------------------
// bf16 MFMA GEMM (R10 version — measured best): C = A @ W^T + bias.
// BM=64, BN=128, BK=32; 4 waves 2(m)x2(n), wave tile 32x64, acc[2][4].
// mode 0: C bf16 [m][1024];  mode 1: C bf16 transposed [n][Mrows];  mode 2: C f32
// ---------------------------------------------------------------------------
__global__ __launch_bounds__(256)
void gemm_mfma(const short* __restrict__ A,
               const short* __restrict__ W0, const float* __restrict__ b0, void* C0,
               const short* __restrict__ W1, const float* __restrict__ b1, void* C1,
               const short* __restrict__ W2, const float* __restrict__ b2, void* C2,
               int m0_, int m1_, int m2_, int Mrows)
{
    const short* W; const float* bias; void* C; int mode;
    if (blockIdx.z == 0)      { W = W0; bias = b0; C = C0; mode = m0_; }
    else if (blockIdx.z == 1) { W = W1; bias = b1; C = C1; mode = m1_; }
    else                      { W = W2; bias = b2; C = C2; mode = m2_; }

    __shared__ short As[64][40];     // 32 k-cols + 4 pad -> 80B rows
    __shared__ short Bs[128][40];

    const int tid = threadIdx.x;
    const int wave = tid >> 6, lane = tid & 63;
    const int l15 = lane & 15, l4 = lane >> 4;
    const int wm = wave >> 1, wn = wave & 1;
    const int m0 = blockIdx.y * 64, n0 = blockIdx.x * 128;

    const int srow = tid >> 2;            // 0..63
    const int scol = (tid & 3) * 16;      // byte col within 64B k-row

    f32x4 acc[2][4];
#pragma unroll
    for (int i = 0; i < 2; ++i)
#pragma unroll
        for (int j = 0; j < 4; ++j) acc[i][j] = (f32x4){0.f,0.f,0.f,0.f};

    int4v apre, bpre0, bpre1;
    apre  = *(const int4v*)((const char*)A + (size_t)(m0 + srow) * 2048 + scol);
    bpre0 = *(const int4v*)((const char*)W + (size_t)(n0 + srow) * 2048 + scol);
    bpre1 = *(const int4v*)((const char*)W + (size_t)(n0 + 64 + srow) * 2048 + scol);

    for (int ks = 0; ks < 32; ++ks) {
        __syncthreads();
        *(int4v*)((char*)&As[0][0] + srow * 80 + scol) = apre;
        *(int4v*)((char*)&Bs[0][0] + srow * 80 + scol) = bpre0;
        *(int4v*)((char*)&Bs[0][0] + (64 + srow) * 80 + scol) = bpre1;
        __syncthreads();
        if (ks + 1 < 32) {
            const int kb = (ks + 1) * 64;
            apre  = *(const int4v*)((const char*)A + (size_t)(m0 + srow) * 2048 + kb + scol);
            bpre0 = *(const int4v*)((const char*)W + (size_t)(n0 + srow) * 2048 + kb + scol);
            bpre1 = *(const int4v*)((const char*)W + (size_t)(n0 + 64 + srow) * 2048 + kb + scol);
        }
        bf16x8 af[2], bf[4];
#pragma unroll
        for (int mi = 0; mi < 2; ++mi)
            af[mi] = *(const bf16x8*)((const char*)&As[0][0] + (wm*32 + mi*16 + l15) * 80 + l4*16);
#pragma unroll
        for (int nj = 0; nj < 4; ++nj)
            bf[nj] = *(const bf16x8*)((const char*)&Bs[0][0] + (wn*64 + nj*16 + l15) * 80 + l4*16);
#pragma unroll
        for (int mi = 0; mi < 2; ++mi)
#pragma unroll
            for (int nj = 0; nj < 4; ++nj)
                acc[mi][nj] = MFMA(af[mi], bf[nj], acc[mi][nj]);
    }

#pragma unroll
    for (int nj = 0; nj < 4; ++nj) {
        const int nglob = n0 + wn*64 + nj*16 + l15;
        const float bn = bias[nglob];
#pragma unroll
        for (int mi = 0; mi < 2; ++mi) {
            const int mbase = m0 + wm*32 + mi*16 + l4*4;
            if (mode == 0) {
#pragma unroll
                for (int r = 0; r < 4; ++r)
                    ((short*)C)[(size_t)(mbase + r) * 1024 + nglob] = f2bf(acc[mi][nj][r] + bn);
            } else if (mode == 1) {
                bf16x4 pk;
#pragma unroll
                for (int r = 0; r < 4; ++r) pk[r] = f2bf(acc[mi][nj][r] + bn);
                *(bf16x4*)((short*)C + (size_t)nglob * Mrows + mbase) = pk;
            } else {
#pragma unroll
                for (int r = 0; r < 4; ++r)
                    ((float*)C)[(size_t)(mbase + r) * 1024 + nglob] = acc[mi][nj][r] + bn;
            }
        }
    }
}

// ---------------------------------------------------------------------------
// phi2 (MFMA): per block = one (src, head, 64 s-rows)
// ---------------------------------------------------------------------------
__global__ __launch_bounds__(256)
void phi2_kernel(const short* __restrict__ qbuf, const short* __restrict__ kbuf,
                 const short* __restrict__ omtb, const float* __restrict__ rffb,
                 short* __restrict__ Qa, short* __restrict__ Ka)
{
    __shared__ short om[128][72];
    __shared__ float bsh[128];

    const int src = blockIdx.z, h = blockIdx.y;
    const int s0 = blockIdx.x * 64;
    const short* X = src ? kbuf : qbuf;
    short* Out     = src ? Ka : Qa;
    const float fq   = src ? 1.0f : (ALPHA * 0.125f);
    const float fphi = src ? 1.0f : ((1.0f - ALPHA) * 0.125f);

    const int tid = threadIdx.x, wave = tid >> 6, lane = tid & 63;
    const int l15 = lane & 15, l4 = lane >> 4;

    {
        const char* gsrc = (const char*)(omtb + ((size_t)h << 13));
#pragma unroll
        for (int it = 0; it < 4; ++it) {
            int f = tid * 16 + it * 4096;
            int row = f >> 7, colb = f & 127;
            *(int4v*)((char*)&om[0][0] + row * 144 + colb) = *(const int4v*)(gsrc + f);
        }
        if (tid < 128) bsh[tid] = rffb[h * 128 + tid];
    }
    __syncthreads();

    const int srow = s0 + wave * 16 + l15;

    bf16x8 xf[2];
#pragma unroll
    for (int cs = 0; cs < 2; ++cs)
        xf[cs] = *(const bf16x8*)(X + (size_t)srow * HID + h * HD + cs * 32 + l4 * 8);

    float ss = 0.f;
#pragma unroll
    for (int cs = 0; cs < 2; ++cs)
#pragma unroll
        for (int j = 0; j < 8; ++j) { float v = bf2f(xf[cs][j]); ss = fmaf(v, v, ss); }
    ss += __shfl_xor(ss, 16);
    ss += __shfl_xor(ss, 32);
    const float inv = 1.0f / (sqrtf(ss) + 1e-6f);

    bf16x8 qn[2];
#pragma unroll
    for (int cs = 0; cs < 2; ++cs) {
        bf16x8 o, w;
#pragma unroll
        for (int j = 0; j < 8; ++j) {
            float v = bf2f(xf[cs][j]);
            o[j] = f2bf(v * inv);
            w[j] = f2bf(v * fq);
        }
        qn[cs] = o;
        *(bf16x8*)(Out + ((size_t)h * S_LEN + srow) * CAUG + cs * 32 + l4 * 8) = w;
    }

    f32x4 pacc[8];
#pragma unroll
    for (int t = 0; t < 8; ++t) pacc[t] = (f32x4){0.f,0.f,0.f,0.f};
#pragma unroll
    for (int t = 0; t < 8; ++t)
#pragma unroll
        for (int cs = 0; cs < 2; ++cs) {
            bf16x8 bf = *(const bf16x8*)((const char*)&om[0][0] + (t*16 + l15) * 144 + cs*64 + l4*16);
            pacc[t] = MFMA(qn[cs], bf, pacc[t]);
        }

    float ph[8][4];
    float ps[4] = {0.f, 0.f, 0.f, 0.f};
#pragma unroll
    for (int t = 0; t < 8; ++t) {
        const float bv = bsh[t * 16 + l15];
#pragma unroll
        for (int r = 0; r < 4; ++r) {
            float p = pacc[t][r] + bv;
            float c = 0.125f * __cosf(p);
            ph[t][r] = c;
            ps[r] = fmaf(c, c, ps[r]);
        }
    }
#pragma unroll
    for (int r = 0; r < 4; ++r) {
        ps[r] += __shfl_xor(ps[r], 1);
        ps[r] += __shfl_xor(ps[r], 2);
        ps[r] += __shfl_xor(ps[r], 4);
        ps[r] += __shfl_xor(ps[r], 8);
    }
    float inv2[4];
#pragma unroll
    for (int r = 0; r < 4; ++r) inv2[r] = fphi / (sqrtf(ps[r]) + 1e-6f);

#pragma unroll
    for (int t = 0; t < 8; ++t)
#pragma unroll
        for (int r = 0; r < 4; ++r)
            Out[((size_t)h * S_LEN + s0 + wave * 16 + l4 * 4 + r) * CAUG + 64 + t * 16 + l15]
                = f2bf(ph[t][r] * inv2[r]);
}

// ---------------------------------------------------------------------------
// MFMA flash attention (R16 structure + 2-way K-split across blocks).
// Grid (32,16,2) = 1024 blocks -> 3 blocks/CU (LDS-capped: 46KBx3 = 138KB).
// Each block covers ksp's 32 chunks: group g covers 16 (base = ksp*32+g*16).
// XCD swizzle: both K-splits + all q-tiles of a head share one XCD.
// In-block group combine unchanged; block exports bf16 O-partial + f32 l
// (static-max -> plain sums); merge kernel combines the 2 splits.
// ---------------------------------------------------------------------------
__global__ __launch_bounds__(256, 2)
void flash_mfma(const short* __restrict__ Qa, const short* __restrict__ Ka,
                const short* __restrict__ vt, const float* __restrict__ mask,
                short* __restrict__ Opart, float* __restrict__ Lpart)
{
    __shared__ short Ks[2][32][200];   // per-group K chunk: 32 kpos x (192+8) bf16
    __shared__ short Vt[2][64][40];    // per-group V^T chunk: 64 d x (32+8) bf16
    __shared__ short Pl[4][32][40];    // per-wave P: 32 q x (32+8) bf16

    const int tid = threadIdx.x;
    const int wave = tid >> 6, lane = tid & 63;
    const int l15 = lane & 15, l4 = lane >> 4;
    const int g = wave >> 1, sub = wave & 1;

    // XCD-aware swizzle: id%8 = XCD; head pinned to XCD; both ksp halves too.
    const int id = blockIdx.x + 32 * blockIdx.y + 512 * blockIdx.z;  // 0..1023
    const int xcd = id & 7, slot = id >> 3;        // slot 0..127
    const int h   = xcd + 8 * (slot >> 6);         // 2 heads per XCD
    const int rem = slot & 63;
    const int qt  = rem & 31;
    const int ksp = rem >> 5;
    const int q0  = qt * 64 + sub * 32;

    bf16x8 qf[2][6];
#pragma unroll
    for (int qj = 0; qj < 2; ++qj)
#pragma unroll
        for (int cs = 0; cs < 6; ++cs)
            qf[qj][cs] = *(const bf16x8*)(Qa + ((size_t)h * 2048 + q0 + qj*16 + l15) * CAUG + cs*32 + l4*8);

    f32x4 oacc[4][2];
#pragma unroll
    for (int di = 0; di < 4; ++di)
#pragma unroll
        for (int qj = 0; qj < 2; ++qj) oacc[di][qj] = (f32x4){0.f,0.f,0.f,0.f};
    float lsum[2] = {0.f, 0.f};

    const int t = tid & 127;
    int kr[6], kcb[6], vr[2], vcb[2];
#pragma unroll
    for (int it = 0; it < 6; ++it) { int f = t*16 + it*2048; kr[it] = f/384; kcb[it] = f%384; }
#pragma unroll
    for (int it = 0; it < 2; ++it) { int f = t*16 + it*2048; vr[it] = f/64; vcb[it] = f%64; }

    const char* Kg = (const char*)(Ka + (size_t)h * 2048 * CAUG);   // rows 384B
    const char* Vg = (const char*)(vt + (size_t)h * 64 * 2048);     // rows 4096B
    const int base = ksp * 32 + g * 16;   // 16 chunks per group

    int4v kpre[6], vpre[2];
#pragma unroll
    for (int it = 0; it < 6; ++it)
        kpre[it] = *(const int4v*)(Kg + (size_t)base*12288 + (size_t)kr[it]*384 + kcb[it]);
#pragma unroll
    for (int it = 0; it < 2; ++it)
        vpre[it] = *(const int4v*)(Vg + (size_t)vr[it]*4096 + (size_t)base*64 + vcb[it]);

    for (int i = 0; i < 16; ++i) {
        const int kt = base + i;
        __syncthreads();
#pragma unroll
        for (int it = 0; it < 6; ++it)
            *(int4v*)((char*)&Ks[g][0][0] + kr[it]*400 + kcb[it]) = kpre[it];
#pragma unroll
        for (int it = 0; it < 2; ++it)
            *(int4v*)((char*)&Vt[g][0][0] + vr[it]*80 + vcb[it]) = vpre[it];
        __syncthreads();
        if (i + 1 < 16) {
            const size_t ko = (size_t)(kt + 1) * 12288;
            const size_t vo = (size_t)(kt + 1) * 64;
#pragma unroll
            for (int it = 0; it < 6; ++it)
                kpre[it] = *(const int4v*)(Kg + ko + (size_t)kr[it]*384 + kcb[it]);
#pragma unroll
            for (int it = 0; it < 2; ++it)
                vpre[it] = *(const int4v*)(Vg + (size_t)vr[it]*4096 + vo + vcb[it]);
        }

        f32x4 sacc[2][2];
#pragma unroll
        for (int fi = 0; fi < 2; ++fi)
#pragma unroll
            for (int qj = 0; qj < 2; ++qj) sacc[fi][qj] = (f32x4){0.f,0.f,0.f,0.f};
#pragma unroll
        for (int cs = 0; cs < 6; ++cs) {
            bf16x8 ka[2];
#pragma unroll
            for (int fi = 0; fi < 2; ++fi)
                ka[fi] = *(const bf16x8*)((const char*)&Ks[g][0][0] + (fi*16 + l15)*400 + cs*64 + l4*16);
#pragma unroll
            for (int fi = 0; fi < 2; ++fi)
#pragma unroll
                for (int qj = 0; qj < 2; ++qj)
                    sacc[fi][qj] = MFMA(ka[fi], qf[qj][cs], sacc[fi][qj]);
        }
#pragma unroll
        for (int fi = 0; fi < 2; ++fi) {
            float4 mk = *(const float4*)&mask[kt*32 + fi*16 + l4*4];
            float mv[4] = {mk.x * -10000.f, mk.y * -10000.f, mk.z * -10000.f, mk.w * -10000.f};
#pragma unroll
            for (int qj = 0; qj < 2; ++qj) {
                bf16x4 pk;
#pragma unroll
                for (int r = 0; r < 4; ++r) {
                    float p = __expf(sacc[fi][qj][r] + mv[r]);
                    lsum[qj] += p;
                    pk[r] = f2bf(p);
                }
                *(bf16x4*)((char*)&Pl[wave][0][0] + (qj*16 + l15)*80 + fi*32 + l4*8) = pk;
            }
        }
        {
            bf16x8 va[4], pb[2];
#pragma unroll
            for (int di = 0; di < 4; ++di)
                va[di] = *(const bf16x8*)((const char*)&Vt[g][0][0] + (di*16 + l15)*80 + l4*16);
#pragma unroll
            for (int qj = 0; qj < 2; ++qj)
                pb[qj] = *(const bf16x8*)((const char*)&Pl[wave][0][0] + (qj*16 + l15)*80 + l4*16);
#pragma unroll
            for (int di = 0; di < 4; ++di)
#pragma unroll
                for (int qj = 0; qj < 2; ++qj)
                    oacc[di][qj] = MFMA(va[di], pb[qj], oacc[di][qj]);
        }
    }

#pragma unroll
    for (int qj = 0; qj < 2; ++qj) {
        lsum[qj] += __shfl_xor(lsum[qj], 16);
        lsum[qj] += __shfl_xor(lsum[qj], 32);
    }

    // ---- combine the two groups in LDS, export partials ----
    __syncthreads();
    float* scrO = (float*)&Ks[0][0][0];
    float* scrL = (float*)&Vt[0][0][0];
    if (g == 1) {
#pragma unroll
        for (int qj = 0; qj < 2; ++qj) {
#pragma unroll
            for (int di = 0; di < 4; ++di)
                *(f32x4*)&scrO[(size_t)(sub*32 + qj*16 + l15)*68 + di*16 + l4*4] = oacc[di][qj];
            if (l4 == 0) scrL[sub*32 + qj*16 + l15] = lsum[qj];
        }
    }
    __syncthreads();
    if (g == 0) {
#pragma unroll
        for (int qj = 0; qj < 2; ++qj) {
            const float l = lsum[qj] + scrL[sub*32 + qj*16 + l15];
            const size_t orow = (size_t)(ksp * NH + h) * 2048 + q0 + qj*16 + l15;
#pragma unroll
            for (int di = 0; di < 4; ++di) {
                f32x4 o2 = *(const f32x4*)&scrO[(size_t)(sub*32 + qj*16 + l15)*68 + di*16 + l4*4];
                bf16x4 ob;
#pragma unroll
                for (int r = 0; r < 4; ++r) ob[r] = f2bf(oacc[di][qj][r] + o2[r]);
                *(bf16x4*)(Opart + orow * 64 + di*16 + l4*4) = ob;
            }
            if (l4 == 0) Lpart[orow] = l;
        }
    }
}

// ---------------------------------------------------------------------------
// merge the 2 flash K-split partials -> ctx bf16 [s][1024]
// ---------------------------------------------------------------------------
__global__ __launch_bounds__(256)
void merge_kernel(const short* __restrict__ Opart, const float* __restrict__ Lpart,
                  short* __restrict__ ctxb)
{
    int tt = blockIdx.x * 256 + threadIdx.x;      // 524288 threads x 4 elems
    int e = tt * 4;
    int d = e & 63;
    int q = (e >> 6) & 2047;
    int h = e >> 17;
    float acc[4] = {0.f, 0.f, 0.f, 0.f};
    float L = 0.f;
#pragma unroll
    for (int s = 0; s < KSPL; ++s) {
        size_t idx = (size_t)(s * NH + h) * 2048 + q;
        bf16x4 a = *(const bf16x4*)(Opart + idx * 64 + d);
        L += Lpart[idx];
#pragma unroll
        for (int r = 0; r < 4; ++r) acc[r] += bf2f(a[r]);
    }
    float inv = 1.0f / L;
    bf16x4 o;
#pragma unroll
    for (int r = 0; r < 4; ++r) o[r] = f2bf(acc[r] * inv);
    *(bf16x4*)(ctxb + (size_t)q * 1024 + h * 64 + d) = o;
}

// ---------------------------------------------------------------------------
extern "C" void kernel_launch(void* const* d_in, const int* in_sizes, int n_in,
                              void* d_out, int out_size, void* d_ws, size_t ws_size,
                              hipStream_t stream)
{
    const float* hs    = (const float*)d_in[0];
    const float* mask  = (const float*)d_in[1];
    const float* Wq    = (const float*)d_in[2];
    const float* bq    = (const float*)d_in[3];
    const float* Wk    = (const float*)d_in[4];
    const float* bk    = (const float*)d_in[5];
    const float* Wv    = (const float*)d_in[6];
    const float* bv    = (const float*)d_in[7];
    const float* Wo    = (const float*)d_in[8];
    const float* bo    = (const float*)d_in[9];
    const float* omega = (const float*)d_in[10];
    const float* rffb  = (const float*)d_in[11];
    float* out = (float*)d_out;

    short* wsS  = (short*)d_ws;
    short* hsb  = wsS;                       // 2,097,152
    short* wqb  = hsb + 2097152;             // 1,048,576
    short* wkb  = wqb + 1048576;
    short* wvb  = wkb + 1048576;
    short* wob  = wvb + 1048576;
    short* qb   = wob + 1048576;             // 2,097,152
    short* kb   = qb  + 2097152;
    short* vtb  = kb  + 2097152;             // [h][d][s]
    short* ctxb = vtb + 2097152;
    short* QaB  = ctxb+ 2097152;             // 6,291,456  [h][s][192]
    short* KaB  = QaB + 6291456;
    short* omtb = KaB + 6291456;             // 131,072    [h][m][d]
    short* OpS  = omtb+ 131072;              // 4,194,304 bf16 [2][16][2048][64]
    float* LpF  = (float*)(OpS + 4194304);   // 65,536 f32 [2][16][2048]

    conv_kernel<<<6272, 256, 0, stream>>>(hs, Wq, Wk, Wv, Wo, omega,
                                          hsb, wqb, wkb, wvb, wob, omtb);
    gemm_mfma<<<dim3(8, 32, 3), 256, 0, stream>>>(hsb, wqb, bq, qb, wkb, bk, kb, wvb, bv, vtb,
                                                  0, 0, 1, S_LEN);
    phi2_kernel<<<dim3(32, 16, 2), 256, 0, stream>>>(qb, kb, omtb, rffb, QaB, KaB);
    flash_mfma<<<dim3(32, 16, KSPL), 256, 0, stream>>>(QaB, KaB, vtb, mask, OpS, LpF);
    merge_kernel<<<2048, 256, 0, stream>>>(OpS, LpF, ctxb);
    gemm_mfma<<<dim3(8, 32, 1), 256, 0, stream>>>(ctxb, wob, bo, out, wob, bo, out, wob, bo, out,
                                                  2, 2, 2, S_LEN);
}

// Round 19
// 122.732 us; speedup vs baseline: 1.0172x; 1.0172x over previous
//
#include <hip/hip_runtime.h>
#include <math.h>

#define S_LEN 2048
#define HID   1024
#define NH    16
#define HD    64
#define NM    128
#define CAUG  192
#define NCH   32            // flash: chunks (KC=32) per wave-group; 2 groups cover 2048

constexpr float ALPHA = 0.9f;
constexpr float LOG2E = 1.4426950408889634f;

typedef __attribute__((ext_vector_type(8))) short bf16x8;
typedef __attribute__((ext_vector_type(4))) short bf16x4;
typedef __attribute__((ext_vector_type(4))) float f32x4;
typedef __attribute__((ext_vector_type(4))) int   int4v;

#define MFMA(a,b,c) __builtin_amdgcn_mfma_f32_16x16x32_bf16(a,b,c,0,0,0)

static __device__ inline short f2bf(float f) {
    unsigned u = __float_as_uint(f);
    u += 0x7fffu + ((u >> 16) & 1u);      // RNE
    return (short)(u >> 16);
}
static __device__ inline float bf2f(short s) {
    return __uint_as_float(((unsigned)(unsigned short)s) << 16);
}

// ---------------------------------------------------------------------------
// fp32 -> bf16 conversion: hs + 4 weights, float4-wide; tails do the
// omega [h][d][m] -> om_t bf16 [h][m][d] transpose and mask premultiply
// (mask2 = mask * -10000 * log2e, so flash softmax is a bare exp2).
// ---------------------------------------------------------------------------
__global__ __launch_bounds__(256)
void conv_kernel(const float* __restrict__ hs,
                 const float* __restrict__ Wq, const float* __restrict__ Wk,
                 const float* __restrict__ Wv, const float* __restrict__ Wo,
                 const float* __restrict__ omega, const float* __restrict__ mask,
                 short* __restrict__ hsb, short* __restrict__ wqb, short* __restrict__ wkb,
                 short* __restrict__ wvb, short* __restrict__ wob, short* __restrict__ omtb,
                 float* __restrict__ mask2)
{
    int i = blockIdx.x * 256 + threadIdx.x;           // f4-unit index
    if (i >= 1606144) return;
    if (i >= 1605632) {                               // mask premultiply tail
        int j = (i - 1605632) * 4;                    // 0..2047
        float4 v = *(const float4*)(mask + j);
        float4 o = make_float4(v.x * (-10000.f * LOG2E), v.y * (-10000.f * LOG2E),
                               v.z * (-10000.f * LOG2E), v.w * (-10000.f * LOG2E));
        *(float4*)(mask2 + j) = o;
        return;
    }
    if (i >= 1572864) {                               // omega transpose tail
        int j = (i - 1572864) * 4;                    // elem index in [h][d][m]
        int h = j >> 13, rem = j & 8191;
        int d = rem >> 7, m = rem & 127;
        float4 v = *(const float4*)(omega + j);       // 4 consecutive m
        short* dst = omtb + ((h * 128 + m) << 6) + d; // [h][m][d]
        dst[0]       = f2bf(v.x);
        dst[64]      = f2bf(v.y);
        dst[128]     = f2bf(v.z);
        dst[192]     = f2bf(v.w);
        return;
    }
    const float* src; short* dst; int off;
    if (i < 524288) { src = hs; dst = hsb; off = i; }
    else {
        int j = i - 524288;
        int r = j >> 18;              // 0..3
        off = j & 262143;
        src = (r == 0) ? Wq : (r == 1) ? Wk : (r == 2) ? Wv : Wo;
        dst = (r == 0) ? wqb : (r == 1) ? wkb : (r == 2) ? wvb : wob;
    }
    float4 v = ((const float4*)src)[off];
    bf16x4 o; o[0] = f2bf(v.x); o[1] = f2bf(v.y); o[2] = f2bf(v.z); o[3] = f2bf(v.w);
    ((bf16x4*)dst)[off] = o;
}

// ---------------------------------------------------------------------------
// bf16 MFMA GEMM (R10 version — measured best): C = A @ W^T + bias.
// BM=64, BN=128, BK=32; 4 waves 2(m)x2(n), wave tile 32x64, acc[2][4].
// mode 0: C bf16 [m][1024];  mode 1: C bf16 transposed [n][Mrows];  mode 2: C f32
// ---------------------------------------------------------------------------
__global__ __launch_bounds__(256)
void gemm_mfma(const short* __restrict__ A,
               const short* __restrict__ W0, const float* __restrict__ b0, void* C0,
               const short* __restrict__ W1, const float* __restrict__ b1, void* C1,
               const short* __restrict__ W2, const float* __restrict__ b2, void* C2,
               int m0_, int m1_, int m2_, int Mrows)
{
    const short* W; const float* bias; void* C; int mode;
    if (blockIdx.z == 0)      { W = W0; bias = b0; C = C0; mode = m0_; }
    else if (blockIdx.z == 1) { W = W1; bias = b1; C = C1; mode = m1_; }
    else                      { W = W2; bias = b2; C = C2; mode = m2_; }

    __shared__ short As[64][40];     // 32 k-cols + 4 pad -> 80B rows
    __shared__ short Bs[128][40];

    const int tid = threadIdx.x;
    const int wave = tid >> 6, lane = tid & 63;
    const int l15 = lane & 15, l4 = lane >> 4;
    const int wm = wave >> 1, wn = wave & 1;
    const int m0 = blockIdx.y * 64, n0 = blockIdx.x * 128;

    const int srow = tid >> 2;            // 0..63
    const int scol = (tid & 3) * 16;      // byte col within 64B k-row

    f32x4 acc[2][4];
#pragma unroll
    for (int i = 0; i < 2; ++i)
#pragma unroll
        for (int j = 0; j < 4; ++j) acc[i][j] = (f32x4){0.f,0.f,0.f,0.f};

    int4v apre, bpre0, bpre1;
    apre  = *(const int4v*)((const char*)A + (size_t)(m0 + srow) * 2048 + scol);
    bpre0 = *(const int4v*)((const char*)W + (size_t)(n0 + srow) * 2048 + scol);
    bpre1 = *(const int4v*)((const char*)W + (size_t)(n0 + 64 + srow) * 2048 + scol);

    for (int ks = 0; ks < 32; ++ks) {
        __syncthreads();
        *(int4v*)((char*)&As[0][0] + srow * 80 + scol) = apre;
        *(int4v*)((char*)&Bs[0][0] + srow * 80 + scol) = bpre0;
        *(int4v*)((char*)&Bs[0][0] + (64 + srow) * 80 + scol) = bpre1;
        __syncthreads();
        if (ks + 1 < 32) {
            const int kb = (ks + 1) * 64;
            apre  = *(const int4v*)((const char*)A + (size_t)(m0 + srow) * 2048 + kb + scol);
            bpre0 = *(const int4v*)((const char*)W + (size_t)(n0 + srow) * 2048 + kb + scol);
            bpre1 = *(const int4v*)((const char*)W + (size_t)(n0 + 64 + srow) * 2048 + kb + scol);
        }
        bf16x8 af[2], bf[4];
#pragma unroll
        for (int mi = 0; mi < 2; ++mi)
            af[mi] = *(const bf16x8*)((const char*)&As[0][0] + (wm*32 + mi*16 + l15) * 80 + l4*16);
#pragma unroll
        for (int nj = 0; nj < 4; ++nj)
            bf[nj] = *(const bf16x8*)((const char*)&Bs[0][0] + (wn*64 + nj*16 + l15) * 80 + l4*16);
#pragma unroll
        for (int mi = 0; mi < 2; ++mi)
#pragma unroll
            for (int nj = 0; nj < 4; ++nj)
                acc[mi][nj] = MFMA(af[mi], bf[nj], acc[mi][nj]);
    }

#pragma unroll
    for (int nj = 0; nj < 4; ++nj) {
        const int nglob = n0 + wn*64 + nj*16 + l15;
        const float bn = bias[nglob];
#pragma unroll
        for (int mi = 0; mi < 2; ++mi) {
            const int mbase = m0 + wm*32 + mi*16 + l4*4;
            if (mode == 0) {
#pragma unroll
                for (int r = 0; r < 4; ++r)
                    ((short*)C)[(size_t)(mbase + r) * 1024 + nglob] = f2bf(acc[mi][nj][r] + bn);
            } else if (mode == 1) {
                bf16x4 pk;
#pragma unroll
                for (int r = 0; r < 4; ++r) pk[r] = f2bf(acc[mi][nj][r] + bn);
                *(bf16x4*)((short*)C + (size_t)nglob * Mrows + mbase) = pk;
            } else {
#pragma unroll
                for (int r = 0; r < 4; ++r)
                    ((float*)C)[(size_t)(mbase + r) * 1024 + nglob] = acc[mi][nj][r] + bn;
            }
        }
    }
}

// ---------------------------------------------------------------------------
// phi2 (MFMA): per block = one (src, head, 64 s-rows).
// Qa factors carry an extra LOG2E so flash softmax can use bare exp2.
// ---------------------------------------------------------------------------
__global__ __launch_bounds__(256)
void phi2_kernel(const short* __restrict__ qbuf, const short* __restrict__ kbuf,
                 const short* __restrict__ omtb, const float* __restrict__ rffb,
                 short* __restrict__ Qa, short* __restrict__ Ka)
{
    __shared__ short om[128][72];
    __shared__ float bsh[128];

    const int src = blockIdx.z, h = blockIdx.y;
    const int s0 = blockIdx.x * 64;
    const short* X = src ? kbuf : qbuf;
    short* Out     = src ? Ka : Qa;
    const float fq   = src ? 1.0f : (ALPHA * 0.125f * LOG2E);
    const float fphi = src ? 1.0f : ((1.0f - ALPHA) * 0.125f * LOG2E);

    const int tid = threadIdx.x, wave = tid >> 6, lane = tid & 63;
    const int l15 = lane & 15, l4 = lane >> 4;

    {
        const char* gsrc = (const char*)(omtb + ((size_t)h << 13));
#pragma unroll
        for (int it = 0; it < 4; ++it) {
            int f = tid * 16 + it * 4096;
            int row = f >> 7, colb = f & 127;
            *(int4v*)((char*)&om[0][0] + row * 144 + colb) = *(const int4v*)(gsrc + f);
        }
        if (tid < 128) bsh[tid] = rffb[h * 128 + tid];
    }
    __syncthreads();

    const int srow = s0 + wave * 16 + l15;

    bf16x8 xf[2];
#pragma unroll
    for (int cs = 0; cs < 2; ++cs)
        xf[cs] = *(const bf16x8*)(X + (size_t)srow * HID + h * HD + cs * 32 + l4 * 8);

    float ss = 0.f;
#pragma unroll
    for (int cs = 0; cs < 2; ++cs)
#pragma unroll
        for (int j = 0; j < 8; ++j) { float v = bf2f(xf[cs][j]); ss = fmaf(v, v, ss); }
    ss += __shfl_xor(ss, 16);
    ss += __shfl_xor(ss, 32);
    const float inv = 1.0f / (sqrtf(ss) + 1e-6f);

    bf16x8 qn[2];
#pragma unroll
    for (int cs = 0; cs < 2; ++cs) {
        bf16x8 o, w;
#pragma unroll
        for (int j = 0; j < 8; ++j) {
            float v = bf2f(xf[cs][j]);
            o[j] = f2bf(v * inv);
            w[j] = f2bf(v * fq);
        }
        qn[cs] = o;
        *(bf16x8*)(Out + ((size_t)h * S_LEN + srow) * CAUG + cs * 32 + l4 * 8) = w;
    }

    f32x4 pacc[8];
#pragma unroll
    for (int t = 0; t < 8; ++t) pacc[t] = (f32x4){0.f,0.f,0.f,0.f};
#pragma unroll
    for (int t = 0; t < 8; ++t)
#pragma unroll
        for (int cs = 0; cs < 2; ++cs) {
            bf16x8 bf = *(const bf16x8*)((const char*)&om[0][0] + (t*16 + l15) * 144 + cs*64 + l4*16);
            pacc[t] = MFMA(qn[cs], bf, pacc[t]);
        }

    float ph[8][4];
    float ps[4] = {0.f, 0.f, 0.f, 0.f};
#pragma unroll
    for (int t = 0; t < 8; ++t) {
        const float bv = bsh[t * 16 + l15];
#pragma unroll
        for (int r = 0; r < 4; ++r) {
            float p = pacc[t][r] + bv;
            float c = 0.125f * __cosf(p);
            ph[t][r] = c;
            ps[r] = fmaf(c, c, ps[r]);
        }
    }
#pragma unroll
    for (int r = 0; r < 4; ++r) {
        ps[r] += __shfl_xor(ps[r], 1);
        ps[r] += __shfl_xor(ps[r], 2);
        ps[r] += __shfl_xor(ps[r], 4);
        ps[r] += __shfl_xor(ps[r], 8);
    }
    float inv2[4];
#pragma unroll
    for (int r = 0; r < 4; ++r) inv2[r] = fphi / (sqrtf(ps[r]) + 1e-6f);

#pragma unroll
    for (int t = 0; t < 8; ++t)
#pragma unroll
        for (int r = 0; r < 4; ++r)
            Out[((size_t)h * S_LEN + s0 + wave * 16 + l4 * 4 + r) * CAUG + 64 + t * 16 + l15]
                = f2bf(ph[t][r] * inv2[r]);
}

// ---------------------------------------------------------------------------
// MFMA flash attention (R16 structure: XCD head-grouping swizzle, direct ctx
// write) + s_setprio around MFMA clusters + bare-exp2 softmax (factors folded).
// ---------------------------------------------------------------------------
__global__ __launch_bounds__(256, 2)
void flash_mfma(const short* __restrict__ Qa, const short* __restrict__ Ka,
                const short* __restrict__ vt, const float* __restrict__ mask2,
                short* __restrict__ ctxb)
{
    __shared__ short Ks[2][32][200];   // per-group K chunk: 32 kpos x (192+8) bf16
    __shared__ short Vt[2][64][40];    // per-group V^T chunk: 64 d x (32+8) bf16
    __shared__ short Pl[4][32][40];    // per-wave P: 32 q x (32+8) bf16

    const int tid = threadIdx.x;
    const int wave = tid >> 6, lane = tid & 63;
    const int l15 = lane & 15, l4 = lane >> 4;
    const int g = wave >> 1, sub = wave & 1;

    // XCD-aware swizzle: id%8 selects XCD; head pinned to XCD (2 heads/XCD).
    const int id = blockIdx.x + 32 * blockIdx.y;   // 0..511
    const int xcd = id & 7, slot = id >> 3;        // slot 0..63
    const int h  = xcd + 8 * (slot >> 5);
    const int qt = slot & 31;
    const int q0 = qt * 64 + sub * 32;

    bf16x8 qf[2][6];
#pragma unroll
    for (int qj = 0; qj < 2; ++qj)
#pragma unroll
        for (int cs = 0; cs < 6; ++cs)
            qf[qj][cs] = *(const bf16x8*)(Qa + ((size_t)h * 2048 + q0 + qj*16 + l15) * CAUG + cs*32 + l4*8);

    f32x4 oacc[4][2];
#pragma unroll
    for (int di = 0; di < 4; ++di)
#pragma unroll
        for (int qj = 0; qj < 2; ++qj) oacc[di][qj] = (f32x4){0.f,0.f,0.f,0.f};
    float lsum[2] = {0.f, 0.f};

    const int t = tid & 127;
    int kr[6], kcb[6], vr[2], vcb[2];
#pragma unroll
    for (int it = 0; it < 6; ++it) { int f = t*16 + it*2048; kr[it] = f/384; kcb[it] = f%384; }
#pragma unroll
    for (int it = 0; it < 2; ++it) { int f = t*16 + it*2048; vr[it] = f/64; vcb[it] = f%64; }

    const char* Kg = (const char*)(Ka + (size_t)h * 2048 * CAUG);   // rows 384B
    const char* Vg = (const char*)(vt + (size_t)h * 64 * 2048);     // rows 4096B

    int4v kpre[6], vpre[2];
#pragma unroll
    for (int it = 0; it < 6; ++it)
        kpre[it] = *(const int4v*)(Kg + (size_t)(g*NCH)*12288 + (size_t)kr[it]*384 + kcb[it]);
#pragma unroll
    for (int it = 0; it < 2; ++it)
        vpre[it] = *(const int4v*)(Vg + (size_t)vr[it]*4096 + (size_t)(g*NCH)*64 + vcb[it]);

    for (int i = 0; i < NCH; ++i) {
        const int kt = g * NCH + i;
        __syncthreads();
#pragma unroll
        for (int it = 0; it < 6; ++it)
            *(int4v*)((char*)&Ks[g][0][0] + kr[it]*400 + kcb[it]) = kpre[it];
#pragma unroll
        for (int it = 0; it < 2; ++it)
            *(int4v*)((char*)&Vt[g][0][0] + vr[it]*80 + vcb[it]) = vpre[it];
        __syncthreads();
        if (i + 1 < NCH) {
            const size_t ko = (size_t)(kt + 1) * 12288;
            const size_t vo = (size_t)(kt + 1) * 64;
#pragma unroll
            for (int it = 0; it < 6; ++it)
                kpre[it] = *(const int4v*)(Kg + ko + (size_t)kr[it]*384 + kcb[it]);
#pragma unroll
            for (int it = 0; it < 2; ++it)
                vpre[it] = *(const int4v*)(Vg + (size_t)vr[it]*4096 + vo + vcb[it]);
        }

        f32x4 sacc[2][2];
#pragma unroll
        for (int fi = 0; fi < 2; ++fi)
#pragma unroll
            for (int qj = 0; qj < 2; ++qj) sacc[fi][qj] = (f32x4){0.f,0.f,0.f,0.f};
        __builtin_amdgcn_s_setprio(1);
#pragma unroll
        for (int cs = 0; cs < 6; ++cs) {
            bf16x8 ka[2];
#pragma unroll
            for (int fi = 0; fi < 2; ++fi)
                ka[fi] = *(const bf16x8*)((const char*)&Ks[g][0][0] + (fi*16 + l15)*400 + cs*64 + l4*16);
#pragma unroll
            for (int fi = 0; fi < 2; ++fi)
#pragma unroll
                for (int qj = 0; qj < 2; ++qj)
                    sacc[fi][qj] = MFMA(ka[fi], qf[qj][cs], sacc[fi][qj]);
        }
        __builtin_amdgcn_s_setprio(0);
#pragma unroll
        for (int fi = 0; fi < 2; ++fi) {
            float4 mk = *(const float4*)&mask2[kt*32 + fi*16 + l4*4];
            float mv[4] = {mk.x, mk.y, mk.z, mk.w};
#pragma unroll
            for (int qj = 0; qj < 2; ++qj) {
                bf16x4 pk;
#pragma unroll
                for (int r = 0; r < 4; ++r) {
                    float p = exp2f(sacc[fi][qj][r] + mv[r]);
                    lsum[qj] += p;
                    pk[r] = f2bf(p);
                }
                *(bf16x4*)((char*)&Pl[wave][0][0] + (qj*16 + l15)*80 + fi*32 + l4*8) = pk;
            }
        }
        {
            bf16x8 va[4], pb[2];
#pragma unroll
            for (int di = 0; di < 4; ++di)
                va[di] = *(const bf16x8*)((const char*)&Vt[g][0][0] + (di*16 + l15)*80 + l4*16);
#pragma unroll
            for (int qj = 0; qj < 2; ++qj)
                pb[qj] = *(const bf16x8*)((const char*)&Pl[wave][0][0] + (qj*16 + l15)*80 + l4*16);
            __builtin_amdgcn_s_setprio(1);
#pragma unroll
            for (int di = 0; di < 4; ++di)
#pragma unroll
                for (int qj = 0; qj < 2; ++qj)
                    oacc[di][qj] = MFMA(va[di], pb[qj], oacc[di][qj]);
            __builtin_amdgcn_s_setprio(0);
        }
    }

#pragma unroll
    for (int qj = 0; qj < 2; ++qj) {
        lsum[qj] += __shfl_xor(lsum[qj], 16);
        lsum[qj] += __shfl_xor(lsum[qj], 32);
    }

    __syncthreads();
    float* scrO = (float*)&Ks[0][0][0];
    float* scrL = (float*)&Vt[0][0][0];
    if (g == 1) {
#pragma unroll
        for (int qj = 0; qj < 2; ++qj) {
#pragma unroll
            for (int di = 0; di < 4; ++di)
                *(f32x4*)&scrO[(size_t)(sub*32 + qj*16 + l15)*68 + di*16 + l4*4] = oacc[di][qj];
            if (l4 == 0) scrL[sub*32 + qj*16 + l15] = lsum[qj];
        }
    }
    __syncthreads();
    if (g == 0) {
#pragma unroll
        for (int qj = 0; qj < 2; ++qj) {
            const float l = lsum[qj] + scrL[sub*32 + qj*16 + l15];
            const float inv = 1.0f / l;
            const int s = q0 + qj*16 + l15;
#pragma unroll
            for (int di = 0; di < 4; ++di) {
                f32x4 o2 = *(const f32x4*)&scrO[(size_t)(sub*32 + qj*16 + l15)*68 + di*16 + l4*4];
                bf16x4 ob;
#pragma unroll
                for (int r = 0; r < 4; ++r) ob[r] = f2bf((oacc[di][qj][r] + o2[r]) * inv);
                *(bf16x4*)(ctxb + (size_t)s * HID + h*64 + di*16 + l4*4) = ob;
            }
        }
    }
}

// ---------------------------------------------------------------------------
extern "C" void kernel_launch(void* const* d_in, const int* in_sizes, int n_in,
                              void* d_out, int out_size, void* d_ws, size_t ws_size,
                              hipStream_t stream)
{
    const float* hs    = (const float*)d_in[0];
    const float* mask  = (const float*)d_in[1];
    const float* Wq    = (const float*)d_in[2];
    const float* bq    = (const float*)d_in[3];
    const float* Wk    = (const float*)d_in[4];
    const float* bk    = (const float*)d_in[5];
    const float* Wv    = (const float*)d_in[6];
    const float* bv    = (const float*)d_in[7];
    const float* Wo    = (const float*)d_in[8];
    const float* bo    = (const float*)d_in[9];
    const float* omega = (const float*)d_in[10];
    const float* rffb  = (const float*)d_in[11];
    float* out = (float*)d_out;

    short* wsS  = (short*)d_ws;
    short* hsb  = wsS;                       // 2,097,152
    short* wqb  = hsb + 2097152;             // 1,048,576
    short* wkb  = wqb + 1048576;
    short* wvb  = wkb + 1048576;
    short* wob  = wvb + 1048576;
    short* qb   = wob + 1048576;             // 2,097,152
    short* kb   = qb  + 2097152;
    short* vtb  = kb  + 2097152;             // [h][d][s]
    short* ctxb = vtb + 2097152;
    short* QaB  = ctxb+ 2097152;             // 6,291,456  [h][s][192]
    short* KaB  = QaB + 6291456;
    short* omtb = KaB + 6291456;             // 131,072    [h][m][d]
    float* mask2= (float*)(omtb + 131072);   // 2,048 f32

    conv_kernel<<<6276, 256, 0, stream>>>(hs, Wq, Wk, Wv, Wo, omega, mask,
                                          hsb, wqb, wkb, wvb, wob, omtb, mask2);
    gemm_mfma<<<dim3(8, 32, 3), 256, 0, stream>>>(hsb, wqb, bq, qb, wkb, bk, kb, wvb, bv, vtb,
                                                  0, 0, 1, S_LEN);
    phi2_kernel<<<dim3(32, 16, 2), 256, 0, stream>>>(qb, kb, omtb, rffb, QaB, KaB);
    flash_mfma<<<dim3(32, 16), 256, 0, stream>>>(QaB, KaB, vtb, mask2, ctxb);
    gemm_mfma<<<dim3(8, 32, 1), 256, 0, stream>>>(ctxb, wob, bo, out, wob, bo, out, wob, bo, out,
                                                  2, 2, 2, S_LEN);
}

// Round 20
// 117.784 us; speedup vs baseline: 1.0599x; 1.0420x over previous
//
#include <hip/hip_runtime.h>
#include <math.h>

#define S_LEN 2048
#define HID   1024
#define NH    16
#define HD    64
#define NM    128
#define CAUG  192
#define NCH   32            // flash: chunks (KC=32) per wave-group; 2 groups cover 2048

constexpr float ALPHA = 0.9f;

typedef __attribute__((ext_vector_type(8))) short bf16x8;
typedef __attribute__((ext_vector_type(4))) short bf16x4;
typedef __attribute__((ext_vector_type(4))) float f32x4;
typedef __attribute__((ext_vector_type(4))) int   int4v;

#define MFMA(a,b,c) __builtin_amdgcn_mfma_f32_16x16x32_bf16(a,b,c,0,0,0)

static __device__ inline short f2bf(float f) {
    unsigned u = __float_as_uint(f);
    u += 0x7fffu + ((u >> 16) & 1u);      // RNE
    return (short)(u >> 16);
}
static __device__ inline float bf2f(short s) {
    return __uint_as_float(((unsigned)(unsigned short)s) << 16);
}

// ---------------------------------------------------------------------------
// fp32 -> bf16 conversion: hs + 4 weights, float4-wide; tail range does the
// omega [h][d][m] -> om_t bf16 [h][m][d] transpose.
// ---------------------------------------------------------------------------
__global__ __launch_bounds__(256)
void conv_kernel(const float* __restrict__ hs,
                 const float* __restrict__ Wq, const float* __restrict__ Wk,
                 const float* __restrict__ Wv, const float* __restrict__ Wo,
                 const float* __restrict__ omega,
                 short* __restrict__ hsb, short* __restrict__ wqb, short* __restrict__ wkb,
                 short* __restrict__ wvb, short* __restrict__ wob, short* __restrict__ omtb)
{
    int i = blockIdx.x * 256 + threadIdx.x;           // f4-unit index
    if (i >= 1605632) return;
    if (i >= 1572864) {                               // omega transpose tail
        int j = (i - 1572864) * 4;                    // elem index in [h][d][m]
        int h = j >> 13, rem = j & 8191;
        int d = rem >> 7, m = rem & 127;
        float4 v = *(const float4*)(omega + j);       // 4 consecutive m
        short* dst = omtb + ((h * 128 + m) << 6) + d; // [h][m][d]
        dst[0]       = f2bf(v.x);
        dst[64]      = f2bf(v.y);
        dst[128]     = f2bf(v.z);
        dst[192]     = f2bf(v.w);
        return;
    }
    const float* src; short* dst; int off;
    if (i < 524288) { src = hs; dst = hsb; off = i; }
    else {
        int j = i - 524288;
        int r = j >> 18;              // 0..3
        off = j & 262143;
        src = (r == 0) ? Wq : (r == 1) ? Wk : (r == 2) ? Wv : Wo;
        dst = (r == 0) ? wqb : (r == 1) ? wkb : (r == 2) ? wvb : wob;
    }
    float4 v = ((const float4*)src)[off];
    bf16x4 o; o[0] = f2bf(v.x); o[1] = f2bf(v.y); o[2] = f2bf(v.z); o[3] = f2bf(v.w);
    ((bf16x4*)dst)[off] = o;
}

// ---------------------------------------------------------------------------
// bf16 MFMA GEMM (R10 version — measured best): C = A @ W^T + bias.
// BM=64, BN=128, BK=32; 4 waves 2(m)x2(n), wave tile 32x64, acc[2][4].
// mode 0: C bf16 [m][1024];  mode 1: C bf16 transposed [n][Mrows];  mode 2: C f32
// ---------------------------------------------------------------------------
__global__ __launch_bounds__(256)
void gemm_mfma(const short* __restrict__ A,
               const short* __restrict__ W0, const float* __restrict__ b0, void* C0,
               const short* __restrict__ W1, const float* __restrict__ b1, void* C1,
               const short* __restrict__ W2, const float* __restrict__ b2, void* C2,
               int m0_, int m1_, int m2_, int Mrows)
{
    const short* W; const float* bias; void* C; int mode;
    if (blockIdx.z == 0)      { W = W0; bias = b0; C = C0; mode = m0_; }
    else if (blockIdx.z == 1) { W = W1; bias = b1; C = C1; mode = m1_; }
    else                      { W = W2; bias = b2; C = C2; mode = m2_; }

    __shared__ short As[64][40];     // 32 k-cols + 4 pad -> 80B rows
    __shared__ short Bs[128][40];

    const int tid = threadIdx.x;
    const int wave = tid >> 6, lane = tid & 63;
    const int l15 = lane & 15, l4 = lane >> 4;
    const int wm = wave >> 1, wn = wave & 1;
    const int m0 = blockIdx.y * 64, n0 = blockIdx.x * 128;

    const int srow = tid >> 2;            // 0..63
    const int scol = (tid & 3) * 16;      // byte col within 64B k-row

    f32x4 acc[2][4];
#pragma unroll
    for (int i = 0; i < 2; ++i)
#pragma unroll
        for (int j = 0; j < 4; ++j) acc[i][j] = (f32x4){0.f,0.f,0.f,0.f};

    int4v apre, bpre0, bpre1;
    apre  = *(const int4v*)((const char*)A + (size_t)(m0 + srow) * 2048 + scol);
    bpre0 = *(const int4v*)((const char*)W + (size_t)(n0 + srow) * 2048 + scol);
    bpre1 = *(const int4v*)((const char*)W + (size_t)(n0 + 64 + srow) * 2048 + scol);

    for (int ks = 0; ks < 32; ++ks) {
        __syncthreads();
        *(int4v*)((char*)&As[0][0] + srow * 80 + scol) = apre;
        *(int4v*)((char*)&Bs[0][0] + srow * 80 + scol) = bpre0;
        *(int4v*)((char*)&Bs[0][0] + (64 + srow) * 80 + scol) = bpre1;
        __syncthreads();
        if (ks + 1 < 32) {
            const int kb = (ks + 1) * 64;
            apre  = *(const int4v*)((const char*)A + (size_t)(m0 + srow) * 2048 + kb + scol);
            bpre0 = *(const int4v*)((const char*)W + (size_t)(n0 + srow) * 2048 + kb + scol);
            bpre1 = *(const int4v*)((const char*)W + (size_t)(n0 + 64 + srow) * 2048 + kb + scol);
        }
        bf16x8 af[2], bf[4];
#pragma unroll
        for (int mi = 0; mi < 2; ++mi)
            af[mi] = *(const bf16x8*)((const char*)&As[0][0] + (wm*32 + mi*16 + l15) * 80 + l4*16);
#pragma unroll
        for (int nj = 0; nj < 4; ++nj)
            bf[nj] = *(const bf16x8*)((const char*)&Bs[0][0] + (wn*64 + nj*16 + l15) * 80 + l4*16);
#pragma unroll
        for (int mi = 0; mi < 2; ++mi)
#pragma unroll
            for (int nj = 0; nj < 4; ++nj)
                acc[mi][nj] = MFMA(af[mi], bf[nj], acc[mi][nj]);
    }

#pragma unroll
    for (int nj = 0; nj < 4; ++nj) {
        const int nglob = n0 + wn*64 + nj*16 + l15;
        const float bn = bias[nglob];
#pragma unroll
        for (int mi = 0; mi < 2; ++mi) {
            const int mbase = m0 + wm*32 + mi*16 + l4*4;
            if (mode == 0) {
#pragma unroll
                for (int r = 0; r < 4; ++r)
                    ((short*)C)[(size_t)(mbase + r) * 1024 + nglob] = f2bf(acc[mi][nj][r] + bn);
            } else if (mode == 1) {
                bf16x4 pk;
#pragma unroll
                for (int r = 0; r < 4; ++r) pk[r] = f2bf(acc[mi][nj][r] + bn);
                *(bf16x4*)((short*)C + (size_t)nglob * Mrows + mbase) = pk;
            } else {
#pragma unroll
                for (int r = 0; r < 4; ++r)
                    ((float*)C)[(size_t)(mbase + r) * 1024 + nglob] = acc[mi][nj][r] + bn;
            }
        }
    }
}

// ---------------------------------------------------------------------------
// phi2 (MFMA): per block = one (src, head, 64 s-rows)
// ---------------------------------------------------------------------------
__global__ __launch_bounds__(256)
void phi2_kernel(const short* __restrict__ qbuf, const short* __restrict__ kbuf,
                 const short* __restrict__ omtb, const float* __restrict__ rffb,
                 short* __restrict__ Qa, short* __restrict__ Ka)
{
    __shared__ short om[128][72];
    __shared__ float bsh[128];

    const int src = blockIdx.z, h = blockIdx.y;
    const int s0 = blockIdx.x * 64;
    const short* X = src ? kbuf : qbuf;
    short* Out     = src ? Ka : Qa;
    const float fq   = src ? 1.0f : (ALPHA * 0.125f);
    const float fphi = src ? 1.0f : ((1.0f - ALPHA) * 0.125f);

    const int tid = threadIdx.x, wave = tid >> 6, lane = tid & 63;
    const int l15 = lane & 15, l4 = lane >> 4;

    {
        const char* gsrc = (const char*)(omtb + ((size_t)h << 13));
#pragma unroll
        for (int it = 0; it < 4; ++it) {
            int f = tid * 16 + it * 4096;
            int row = f >> 7, colb = f & 127;
            *(int4v*)((char*)&om[0][0] + row * 144 + colb) = *(const int4v*)(gsrc + f);
        }
        if (tid < 128) bsh[tid] = rffb[h * 128 + tid];
    }
    __syncthreads();

    const int srow = s0 + wave * 16 + l15;

    bf16x8 xf[2];
#pragma unroll
    for (int cs = 0; cs < 2; ++cs)
        xf[cs] = *(const bf16x8*)(X + (size_t)srow * HID + h * HD + cs * 32 + l4 * 8);

    float ss = 0.f;
#pragma unroll
    for (int cs = 0; cs < 2; ++cs)
#pragma unroll
        for (int j = 0; j < 8; ++j) { float v = bf2f(xf[cs][j]); ss = fmaf(v, v, ss); }
    ss += __shfl_xor(ss, 16);
    ss += __shfl_xor(ss, 32);
    const float inv = 1.0f / (sqrtf(ss) + 1e-6f);

    bf16x8 qn[2];
#pragma unroll
    for (int cs = 0; cs < 2; ++cs) {
        bf16x8 o, w;
#pragma unroll
        for (int j = 0; j < 8; ++j) {
            float v = bf2f(xf[cs][j]);
            o[j] = f2bf(v * inv);
            w[j] = f2bf(v * fq);
        }
        qn[cs] = o;
        *(bf16x8*)(Out + ((size_t)h * S_LEN + srow) * CAUG + cs * 32 + l4 * 8) = w;
    }

    f32x4 pacc[8];
#pragma unroll
    for (int t = 0; t < 8; ++t) pacc[t] = (f32x4){0.f,0.f,0.f,0.f};
#pragma unroll
    for (int t = 0; t < 8; ++t)
#pragma unroll
        for (int cs = 0; cs < 2; ++cs) {
            bf16x8 bf = *(const bf16x8*)((const char*)&om[0][0] + (t*16 + l15) * 144 + cs*64 + l4*16);
            pacc[t] = MFMA(qn[cs], bf, pacc[t]);
        }

    float ph[8][4];
    float ps[4] = {0.f, 0.f, 0.f, 0.f};
#pragma unroll
    for (int t = 0; t < 8; ++t) {
        const float bv = bsh[t * 16 + l15];
#pragma unroll
        for (int r = 0; r < 4; ++r) {
            float p = pacc[t][r] + bv;
            float c = 0.125f * __cosf(p);
            ph[t][r] = c;
            ps[r] = fmaf(c, c, ps[r]);
        }
    }
#pragma unroll
    for (int r = 0; r < 4; ++r) {
        ps[r] += __shfl_xor(ps[r], 1);
        ps[r] += __shfl_xor(ps[r], 2);
        ps[r] += __shfl_xor(ps[r], 4);
        ps[r] += __shfl_xor(ps[r], 8);
    }
    float inv2[4];
#pragma unroll
    for (int r = 0; r < 4; ++r) inv2[r] = fphi / (sqrtf(ps[r]) + 1e-6f);

#pragma unroll
    for (int t = 0; t < 8; ++t)
#pragma unroll
        for (int r = 0; r < 4; ++r)
            Out[((size_t)h * S_LEN + s0 + wave * 16 + l4 * 4 + r) * CAUG + 64 + t * 16 + l15]
                = f2bf(ph[t][r] * inv2[r]);
}

// ---------------------------------------------------------------------------
// MFMA flash attention (R16 — measured best 63.2 us).
// Static-max softmax, wave-group K-split in-block, LDS combine at end,
// XCD-aware head-grouping swizzle (head pinned to its XCD's L2).
// ---------------------------------------------------------------------------
__global__ __launch_bounds__(256, 2)
void flash_mfma(const short* __restrict__ Qa, const short* __restrict__ Ka,
                const short* __restrict__ vt, const float* __restrict__ mask,
                short* __restrict__ ctxb)
{
    __shared__ short Ks[2][32][200];   // per-group K chunk: 32 kpos x (192+8) bf16
    __shared__ short Vt[2][64][40];    // per-group V^T chunk: 64 d x (32+8) bf16
    __shared__ short Pl[4][32][40];    // per-wave P: 32 q x (32+8) bf16

    const int tid = threadIdx.x;
    const int wave = tid >> 6, lane = tid & 63;
    const int l15 = lane & 15, l4 = lane >> 4;
    const int g = wave >> 1, sub = wave & 1;

    // XCD-aware swizzle: id%8 selects XCD; head pinned to XCD (2 heads/XCD).
    const int id = blockIdx.x + 32 * blockIdx.y;   // 0..511
    const int xcd = id & 7, slot = id >> 3;        // slot 0..63
    const int h  = xcd + 8 * (slot >> 5);
    const int qt = slot & 31;
    const int q0 = qt * 64 + sub * 32;

    bf16x8 qf[2][6];
#pragma unroll
    for (int qj = 0; qj < 2; ++qj)
#pragma unroll
        for (int cs = 0; cs < 6; ++cs)
            qf[qj][cs] = *(const bf16x8*)(Qa + ((size_t)h * 2048 + q0 + qj*16 + l15) * CAUG + cs*32 + l4*8);

    f32x4 oacc[4][2];
#pragma unroll
    for (int di = 0; di < 4; ++di)
#pragma unroll
        for (int qj = 0; qj < 2; ++qj) oacc[di][qj] = (f32x4){0.f,0.f,0.f,0.f};
    float lsum[2] = {0.f, 0.f};

    const int t = tid & 127;
    int kr[6], kcb[6], vr[2], vcb[2];
#pragma unroll
    for (int it = 0; it < 6; ++it) { int f = t*16 + it*2048; kr[it] = f/384; kcb[it] = f%384; }
#pragma unroll
    for (int it = 0; it < 2; ++it) { int f = t*16 + it*2048; vr[it] = f/64; vcb[it] = f%64; }

    const char* Kg = (const char*)(Ka + (size_t)h * 2048 * CAUG);   // rows 384B
    const char* Vg = (const char*)(vt + (size_t)h * 64 * 2048);     // rows 4096B

    int4v kpre[6], vpre[2];
#pragma unroll
    for (int it = 0; it < 6; ++it)
        kpre[it] = *(const int4v*)(Kg + (size_t)(g*NCH)*12288 + (size_t)kr[it]*384 + kcb[it]);
#pragma unroll
    for (int it = 0; it < 2; ++it)
        vpre[it] = *(const int4v*)(Vg + (size_t)vr[it]*4096 + (size_t)(g*NCH)*64 + vcb[it]);

    for (int i = 0; i < NCH; ++i) {
        const int kt = g * NCH + i;
        __syncthreads();
#pragma unroll
        for (int it = 0; it < 6; ++it)
            *(int4v*)((char*)&Ks[g][0][0] + kr[it]*400 + kcb[it]) = kpre[it];
#pragma unroll
        for (int it = 0; it < 2; ++it)
            *(int4v*)((char*)&Vt[g][0][0] + vr[it]*80 + vcb[it]) = vpre[it];
        __syncthreads();
        if (i + 1 < NCH) {
            const size_t ko = (size_t)(kt + 1) * 12288;
            const size_t vo = (size_t)(kt + 1) * 64;
#pragma unroll
            for (int it = 0; it < 6; ++it)
                kpre[it] = *(const int4v*)(Kg + ko + (size_t)kr[it]*384 + kcb[it]);
#pragma unroll
            for (int it = 0; it < 2; ++it)
                vpre[it] = *(const int4v*)(Vg + (size_t)vr[it]*4096 + vo + vcb[it]);
        }

        f32x4 sacc[2][2];
#pragma unroll
        for (int fi = 0; fi < 2; ++fi)
#pragma unroll
            for (int qj = 0; qj < 2; ++qj) sacc[fi][qj] = (f32x4){0.f,0.f,0.f,0.f};
#pragma unroll
        for (int cs = 0; cs < 6; ++cs) {
            bf16x8 ka[2];
#pragma unroll
            for (int fi = 0; fi < 2; ++fi)
                ka[fi] = *(const bf16x8*)((const char*)&Ks[g][0][0] + (fi*16 + l15)*400 + cs*64 + l4*16);
#pragma unroll
            for (int fi = 0; fi < 2; ++fi)
#pragma unroll
                for (int qj = 0; qj < 2; ++qj)
                    sacc[fi][qj] = MFMA(ka[fi], qf[qj][cs], sacc[fi][qj]);
        }
#pragma unroll
        for (int fi = 0; fi < 2; ++fi) {
            float4 mk = *(const float4*)&mask[kt*32 + fi*16 + l4*4];
            float mv[4] = {mk.x * -10000.f, mk.y * -10000.f, mk.z * -10000.f, mk.w * -10000.f};
#pragma unroll
            for (int qj = 0; qj < 2; ++qj) {
                bf16x4 pk;
#pragma unroll
                for (int r = 0; r < 4; ++r) {
                    float p = __expf(sacc[fi][qj][r] + mv[r]);
                    lsum[qj] += p;
                    pk[r] = f2bf(p);
                }
                *(bf16x4*)((char*)&Pl[wave][0][0] + (qj*16 + l15)*80 + fi*32 + l4*8) = pk;
            }
        }
        {
            bf16x8 va[4], pb[2];
#pragma unroll
            for (int di = 0; di < 4; ++di)
                va[di] = *(const bf16x8*)((const char*)&Vt[g][0][0] + (di*16 + l15)*80 + l4*16);
#pragma unroll
            for (int qj = 0; qj < 2; ++qj)
                pb[qj] = *(const bf16x8*)((const char*)&Pl[wave][0][0] + (qj*16 + l15)*80 + l4*16);
#pragma unroll
            for (int di = 0; di < 4; ++di)
#pragma unroll
                for (int qj = 0; qj < 2; ++qj)
                    oacc[di][qj] = MFMA(va[di], pb[qj], oacc[di][qj]);
        }
    }

#pragma unroll
    for (int qj = 0; qj < 2; ++qj) {
        lsum[qj] += __shfl_xor(lsum[qj], 16);
        lsum[qj] += __shfl_xor(lsum[qj], 32);
    }

    __syncthreads();
    float* scrO = (float*)&Ks[0][0][0];
    float* scrL = (float*)&Vt[0][0][0];
    if (g == 1) {
#pragma unroll
        for (int qj = 0; qj < 2; ++qj) {
#pragma unroll
            for (int di = 0; di < 4; ++di)
                *(f32x4*)&scrO[(size_t)(sub*32 + qj*16 + l15)*68 + di*16 + l4*4] = oacc[di][qj];
            if (l4 == 0) scrL[sub*32 + qj*16 + l15] = lsum[qj];
        }
    }
    __syncthreads();
    if (g == 0) {
#pragma unroll
        for (int qj = 0; qj < 2; ++qj) {
            const float l = lsum[qj] + scrL[sub*32 + qj*16 + l15];
            const float inv = 1.0f / l;
            const int s = q0 + qj*16 + l15;
#pragma unroll
            for (int di = 0; di < 4; ++di) {
                f32x4 o2 = *(const f32x4*)&scrO[(size_t)(sub*32 + qj*16 + l15)*68 + di*16 + l4*4];
                bf16x4 ob;
#pragma unroll
                for (int r = 0; r < 4; ++r) ob[r] = f2bf((oacc[di][qj][r] + o2[r]) * inv);
                *(bf16x4*)(ctxb + (size_t)s * HID + h*64 + di*16 + l4*4) = ob;
            }
        }
    }
}

// ---------------------------------------------------------------------------
extern "C" void kernel_launch(void* const* d_in, const int* in_sizes, int n_in,
                              void* d_out, int out_size, void* d_ws, size_t ws_size,
                              hipStream_t stream)
{
    const float* hs    = (const float*)d_in[0];
    const float* mask  = (const float*)d_in[1];
    const float* Wq    = (const float*)d_in[2];
    const float* bq    = (const float*)d_in[3];
    const float* Wk    = (const float*)d_in[4];
    const float* bk    = (const float*)d_in[5];
    const float* Wv    = (const float*)d_in[6];
    const float* bv    = (const float*)d_in[7];
    const float* Wo    = (const float*)d_in[8];
    const float* bo    = (const float*)d_in[9];
    const float* omega = (const float*)d_in[10];
    const float* rffb  = (const float*)d_in[11];
    float* out = (float*)d_out;

    short* wsS  = (short*)d_ws;
    short* hsb  = wsS;                       // 2,097,152
    short* wqb  = hsb + 2097152;             // 1,048,576
    short* wkb  = wqb + 1048576;
    short* wvb  = wkb + 1048576;
    short* wob  = wvb + 1048576;
    short* qb   = wob + 1048576;             // 2,097,152
    short* kb   = qb  + 2097152;
    short* vtb  = kb  + 2097152;             // [h][d][s]
    short* ctxb = vtb + 2097152;
    short* QaB  = ctxb+ 2097152;             // 6,291,456  [h][s][192]
    short* KaB  = QaB + 6291456;
    short* omtb = KaB + 6291456;             // 131,072    [h][m][d]

    conv_kernel<<<6272, 256, 0, stream>>>(hs, Wq, Wk, Wv, Wo, omega,
                                          hsb, wqb, wkb, wvb, wob, omtb);
    gemm_mfma<<<dim3(8, 32, 3), 256, 0, stream>>>(hsb, wqb, bq, qb, wkb, bk, kb, wvb, bv, vtb,
                                                  0, 0, 1, S_LEN);
    phi2_kernel<<<dim3(32, 16, 2), 256, 0, stream>>>(qb, kb, omtb, rffb, QaB, KaB);
    flash_mfma<<<dim3(32, 16), 256, 0, stream>>>(QaB, KaB, vtb, mask, ctxb);
    gemm_mfma<<<dim3(8, 32, 1), 256, 0, stream>>>(ctxb, wob, bo, out, wob, bo, out, wob, bo, out,
                                                  2, 2, 2, S_LEN);
}